// Round 3
// baseline (657.372 us; speedup 1.0000x reference)
//
#include <hip/hip_runtime.h>
#include <hip/hip_bf16.h>

// Fused 2-layer LSTM (H=32) + linear head, MI355X gfx950.
// Layer-pipelined + batch-split for TLP: 512 WGs x 4 waves, 8 batch rows
// per WG (MFMA M=16, rows 8-15 stay zero). Waves 0-1 = layer 1 @ step s,
// waves 2-3 = layer 2 @ step s-1. One custom barrier per step that drains
// lgkmcnt ONLY (x prefetch stays in flight across it - no vmcnt(0) stall).
// Gates via mfma_f32_16x16x32_bf16 with hi/lo bf16 split (~fp32 exact).

#define T_LEN 512
#define D_IN  28

typedef __attribute__((ext_vector_type(8))) short short8;  // 8 x bf16
typedef __attribute__((ext_vector_type(4))) float f32x4;

__device__ __forceinline__ float fsig(float x) {
  float e = __builtin_amdgcn_exp2f(x * -1.4426950408889634f);
  return __builtin_amdgcn_rcpf(1.0f + e);
}
__device__ __forceinline__ float ftanh(float x) {
  float e = __builtin_amdgcn_exp2f(x * 2.8853900817779268f);
  return 1.0f - 2.0f * __builtin_amdgcn_rcpf(e + 1.0f);
}

// hi = bf16 truncation of x, lo = bf16 of exact residual (x - hi).
__device__ __forceinline__ void split_bf16(float x, short& hi, short& lo) {
  unsigned u = __float_as_uint(x);
  hi = (short)(u >> 16);
  float hf_ = __uint_as_float(u & 0xFFFF0000u);
  float lf = x - hf_;  // exact
  lo = (short)(__float_as_uint(lf) >> 16);
}

// Barrier that does NOT drain vmcnt: LDS producer/consumer ordering only.
__device__ __forceinline__ void lds_barrier() {
  asm volatile("s_waitcnt lgkmcnt(0)\n\ts_barrier" ::: "memory");
}

// B-operand tile (K=32 x N=16) of W (row-major G x ldk), gate rows
// n*16..n*16+15, k zero-padded past kval. Lane l: col=l&15, k=(l>>4)*8..+8.
__device__ __forceinline__ void load_wtile(const float* __restrict__ W, int ldk,
                                           int kval, int n, int lane,
                                           short8& hi, short8& lo) {
  int row = n * 16 + (lane & 15);
  int kb = (lane >> 4) * 8;
  const float* p = W + row * ldk + kb;
#pragma unroll
  for (int i = 0; i < 8; ++i) {
    float v = (kb + i < kval) ? p[i] : 0.0f;
    short h, l;
    split_bf16(v, h, l);
    hi[i] = h; lo[i] = l;
  }
}

#define MFMA(a, b, c) __builtin_amdgcn_mfma_f32_16x16x32_bf16(a, b, c, 0, 0, 0)

__global__ __launch_bounds__(256) void lstm2_pipe(
    const float* __restrict__ x, const float* __restrict__ wih0,
    const float* __restrict__ whh0, const float* __restrict__ wih1,
    const float* __restrict__ whh1, const float* __restrict__ wout,
    const float* __restrict__ bout, float* __restrict__ out) {
  __shared__ short h1buf[2][2][16][40];  // [parity][hi/lo][row][unit pad 40]
  __shared__ short h2buf[2][2][16][40];  // rows 8-15 remain zero forever
  __shared__ float hf[8][33];

  const int tid = threadIdx.x;
  const int lane = tid & 63;
  const int wid = tid >> 6;    // 0..3
  const int layer = wid >> 1;  // 0 => L1 waves, 1 => L2 waves
  const int w01 = wid & 1;     // unit-half within the layer
  const int b0 = blockIdx.x * 8;

  for (int i = tid; i < 2 * 2 * 16 * 40; i += 256) {
    ((short*)h1buf)[i] = 0;
    ((short*)h2buf)[i] = 0;
  }

  const int lrow = lane & 15;  // A-frag row / C-frag col
  const int lgrp = lane >> 4;  // 0..3
  const int kb = lgrp * 8;
  const int uu = lrow + 16 * w01;  // unit owned in elementwise phase
  const bool mrow_valid = (lrow < 8);   // batch rows 8-15 are padding
  const bool erow_valid = (lgrp < 2);   // C-frag rows 0-7 live in lgrp 0,1

  // ---- this wave's layer weights in VGPRs (hi/lo bf16) ----
  const float* Wih = layer ? wih1 : wih0;
  const float* Whh = layer ? whh1 : whh0;
  const int ldk = layer ? 32 : 28;

  short8 Wxh[4], Wxl[4], Whh_[4], Whl[4];
#pragma unroll
  for (int tt = 0; tt < 4; ++tt) {
    int n = tt * 2 + w01;
    load_wtile(Wih, ldk, ldk, n, lane, Wxh[tt], Wxl[tt]);
    load_wtile(Whh, 32, 32, n, lane, Whh_[tt], Whl[tt]);
  }

  float c[4] = {0, 0, 0, 0}, h[4] = {0, 0, 0, 0};

  const float* xrow = x + ((size_t)(b0 + lrow)) * T_LEN * D_IN + kb;
  float4 A0 = make_float4(0, 0, 0, 0), A1 = make_float4(0, 0, 0, 0);
  if (layer == 0 && mrow_valid) {
    A0 = *(const float4*)(xrow);
    if (lgrp < 3) A1 = *(const float4*)(xrow + 4);
  }

  __syncthreads();  // LDS zero-init visible (full sync once is fine)

  for (int s = 0; s < T_LEN + 1; ++s) {
    const int p = s & 1, q = p ^ 1;
    if (layer == 0) {
      if (s < T_LEN) {
        // prefetch x(s+1) - stays in flight across the lds_barrier
        int tn = (s + 1 < T_LEN) ? s + 1 : s;
        float4 N0 = make_float4(0, 0, 0, 0), N1 = make_float4(0, 0, 0, 0);
        if (mrow_valid) {
          N0 = *(const float4*)(xrow + (size_t)tn * D_IN);
          if (lgrp < 3) N1 = *(const float4*)(xrow + (size_t)tn * D_IN + 4);
        }

        short8 xh, xl;
        {
          float xv[8] = {A0.x, A0.y, A0.z, A0.w, A1.x, A1.y, A1.z, A1.w};
#pragma unroll
          for (int i = 0; i < 8; ++i) {
            short hh_, ll_;
            split_bf16(xv[i], hh_, ll_);
            xh[i] = hh_; xl[i] = ll_;
          }
        }
        short8 ph = *(const short8*)&h1buf[q][0][lrow][kb];
        short8 pl = *(const short8*)&h1buf[q][1][lrow][kb];
        f32x4 acc[4];
#pragma unroll
        for (int tt = 0; tt < 4; ++tt) {
          f32x4 a = {0.f, 0.f, 0.f, 0.f};
          f32x4 b = {0.f, 0.f, 0.f, 0.f};
          a = MFMA(xh, Wxh[tt], a);
          a = MFMA(xl, Wxh[tt], a);
          a = MFMA(xh, Wxl[tt], a);
          b = MFMA(ph, Whh_[tt], b);
          b = MFMA(pl, Whh_[tt], b);
          b = MFMA(ph, Whl[tt], b);
          acc[tt] = a + b;
        }
        if (erow_valid) {
#pragma unroll
          for (int r = 0; r < 4; ++r) {
            float ig = fsig(acc[0][r]);
            float fg = fsig(acc[1][r]);
            float gg = ftanh(acc[2][r]);
            float og = fsig(acc[3][r]);
            c[r] = fg * c[r] + ig * gg;
            h[r] = og * ftanh(c[r]);
            short hh_, ll_;
            split_bf16(h[r], hh_, ll_);
            int row = lgrp * 4 + r;
            h1buf[p][0][row][uu] = hh_;
            h1buf[p][1][row][uu] = ll_;
          }
        }
        A0 = N0; A1 = N1;
      }
    } else {
      if (s >= 1) {
        short8 ah = *(const short8*)&h1buf[q][0][lrow][kb];
        short8 al = *(const short8*)&h1buf[q][1][lrow][kb];
        short8 ph = *(const short8*)&h2buf[q][0][lrow][kb];
        short8 pl = *(const short8*)&h2buf[q][1][lrow][kb];
        f32x4 acc[4];
#pragma unroll
        for (int tt = 0; tt < 4; ++tt) {
          f32x4 a = {0.f, 0.f, 0.f, 0.f};
          f32x4 b = {0.f, 0.f, 0.f, 0.f};
          a = MFMA(ah, Wxh[tt], a);
          a = MFMA(al, Wxh[tt], a);
          a = MFMA(ah, Wxl[tt], a);
          b = MFMA(ph, Whh_[tt], b);
          b = MFMA(pl, Whh_[tt], b);
          b = MFMA(ph, Whl[tt], b);
          acc[tt] = a + b;
        }
        if (erow_valid) {
#pragma unroll
          for (int r = 0; r < 4; ++r) {
            float ig = fsig(acc[0][r]);
            float fg = fsig(acc[1][r]);
            float gg = ftanh(acc[2][r]);
            float og = fsig(acc[3][r]);
            c[r] = fg * c[r] + ig * gg;
            h[r] = og * ftanh(c[r]);
            short hh_, ll_;
            split_bf16(h[r], hh_, ll_);
            int row = lgrp * 4 + r;
            h2buf[p][0][row][uu] = hh_;
            h2buf[p][1][row][uu] = ll_;
          }
        }
      }
    }
    lds_barrier();
    // Hazard audit: iter s reads parity q, writes parity p; iter s+1 writes
    // parity q — ordered by this barrier (writers drained own lgkmcnt, and
    // readers' ds_reads completed before their own MFMA consumed them, which
    // happens before their barrier arrival). Global x prefetch intentionally
    // NOT drained here; it is consumed (vmcnt auto-wait) next iteration.
  }

  // ---- epilogue: out = h2(T-1) @ wout^T + bout ----
  __syncthreads();  // full sync: make sure everyone done with loop LDS
  if (layer == 1 && erow_valid) {
#pragma unroll
    for (int r = 0; r < 4; ++r) hf[lgrp * 4 + r][uu] = h[r];
  }
  __syncthreads();

  for (int j = tid; j < 80; j += 256) {
    int row = j / 10, col = j % 10;
    float s = bout[col];
#pragma unroll
    for (int u = 0; u < 32; ++u) s += hf[row][u] * wout[col * 32 + u];
    out[(size_t)(b0 + row) * 10 + col] = s;
  }
}

extern "C" void kernel_launch(void* const* d_in, const int* in_sizes, int n_in,
                              void* d_out, int out_size, void* d_ws, size_t ws_size,
                              hipStream_t stream) {
  const float* x = (const float*)d_in[0];
  const float* wih0 = (const float*)d_in[1];
  const float* whh0 = (const float*)d_in[2];
  const float* wih1 = (const float*)d_in[3];
  const float* whh1 = (const float*)d_in[4];
  const float* wout = (const float*)d_in[5];
  const float* bout = (const float*)d_in[6];
  float* out = (float*)d_out;
  lstm2_pipe<<<512, 256, 0, stream>>>(x, wih0, whh0, wih1, whh1, wout, bout, out);
}

// Round 4
// 449.218 us; speedup vs baseline: 1.4634x; 1.4634x over previous
//
#include <hip/hip_runtime.h>
#include <hip/hip_bf16.h>

// Fused 2-layer LSTM (H=32) + linear head, MI355X gfx950.
// Round-2 structure: 256 WGs x 4 waves, 16 batch rows/WG; waves 0-1 = L1
// at step s, waves 2-3 = L2 at step s-1; one lgkm-only barrier per step.
// Round-4 change: batched + rcp-merged elementwise (7 trans/cell, all
// trans ops batched across the 4 C-rows so latency pipelines).
// Gates via mfma_f32_16x16x32_bf16 with hi/lo bf16 split (~fp32 exact).

#define T_LEN 512
#define D_IN  28

typedef __attribute__((ext_vector_type(8))) short short8;  // 8 x bf16
typedef __attribute__((ext_vector_type(4))) float f32x4;

#define K_SIG 1.4426950408889634f   // 1/ln2   : sigmoid exp arg
#define K_TANH 2.8853900817779268f  // 2/ln2   : tanh exp arg

// hi = bf16 truncation of x, lo = bf16 of exact residual (x - hi).
__device__ __forceinline__ void split_bf16(float x, short& hi, short& lo) {
  unsigned u = __float_as_uint(x);
  hi = (short)(u >> 16);
  float hf_ = __uint_as_float(u & 0xFFFF0000u);
  float lf = x - hf_;  // exact
  lo = (short)(__float_as_uint(lf) >> 16);
}

// Barrier that does NOT drain vmcnt: LDS producer/consumer ordering only.
__device__ __forceinline__ void lds_barrier() {
  asm volatile("s_waitcnt lgkmcnt(0)\n\ts_barrier" ::: "memory");
}

// B-operand tile (K=32 x N=16) of W (row-major G x ldk), gate rows
// n*16..n*16+15, k zero-padded past kval. Lane l: col=l&15, k=(l>>4)*8..+8.
__device__ __forceinline__ void load_wtile(const float* __restrict__ W, int ldk,
                                           int kval, int n, int lane,
                                           short8& hi, short8& lo) {
  int row = n * 16 + (lane & 15);
  int kb = (lane >> 4) * 8;
  const float* p = W + row * ldk + kb;
#pragma unroll
  for (int i = 0; i < 8; ++i) {
    float v = (kb + i < kval) ? p[i] : 0.0f;
    short h, l;
    split_bf16(v, h, l);
    hi[i] = h; lo[i] = l;
  }
}

#define MFMA(a, b, c) __builtin_amdgcn_mfma_f32_16x16x32_bf16(a, b, c, 0, 0, 0)

// Batched LSTM cell update for 4 C-rows. acc[tt][r] = gate (tt: i,f,g,o).
// All exp2 batched (16 independent), then 4 rcp, then 4 exp2, then 4 rcp:
// chain = ~4 trans latencies instead of 4 serial sigmoid chains.
// c' = (c*(1+ei)*(1+eg) + (eg-1)*(1+ef)) / ((1+ei)*(1+eg)*(1+ef))
// h  = (ec-1) / ((1+eo)*(1+ec)),  ec = e^{2c'}
__device__ __forceinline__ void cell_update(const f32x4* acc, float* c, float* h) {
  float ei[4], ef[4], eg[4], eo[4];
#pragma unroll
  for (int r = 0; r < 4; ++r) {
    ei[r] = __builtin_amdgcn_exp2f(acc[0][r] * -K_SIG);
    ef[r] = __builtin_amdgcn_exp2f(acc[1][r] * -K_SIG);
    eg[r] = __builtin_amdgcn_exp2f(acc[2][r] * K_TANH);
    eo[r] = __builtin_amdgcn_exp2f(acc[3][r] * -K_SIG);
  }
  float cn[4];
#pragma unroll
  for (int r = 0; r < 4; ++r) {
    float pig = (1.0f + ei[r]) * (1.0f + eg[r]);
    float num = c[r] * pig + (eg[r] - 1.0f) * (1.0f + ef[r]);
    float R = __builtin_amdgcn_rcpf(pig * (1.0f + ef[r]));
    cn[r] = num * R;
  }
  float ec[4];
#pragma unroll
  for (int r = 0; r < 4; ++r) ec[r] = __builtin_amdgcn_exp2f(cn[r] * K_TANH);
#pragma unroll
  for (int r = 0; r < 4; ++r) {
    float R2 = __builtin_amdgcn_rcpf((1.0f + eo[r]) * (1.0f + ec[r]));
    c[r] = cn[r];
    h[r] = (ec[r] - 1.0f) * R2;
  }
}

__global__ __launch_bounds__(256) void lstm2_pipe(
    const float* __restrict__ x, const float* __restrict__ wih0,
    const float* __restrict__ whh0, const float* __restrict__ wih1,
    const float* __restrict__ whh1, const float* __restrict__ wout,
    const float* __restrict__ bout, float* __restrict__ out) {
  __shared__ short h1buf[2][2][16][40];  // [parity][hi/lo][row][unit pad 40]
  __shared__ short h2buf[2][2][16][40];
  __shared__ float hf[16][33];

  const int tid = threadIdx.x;
  const int lane = tid & 63;
  const int wid = tid >> 6;    // 0..3
  const int layer = wid >> 1;  // 0 => L1 waves, 1 => L2 waves
  const int w01 = wid & 1;     // unit-half within the layer
  const int b0 = blockIdx.x * 16;

  for (int i = tid; i < 2 * 2 * 16 * 40; i += 256) {
    ((short*)h1buf)[i] = 0;
    ((short*)h2buf)[i] = 0;
  }

  const int lrow = lane & 15;  // A-frag row / C-frag col
  const int lgrp = lane >> 4;  // 0..3
  const int kb = lgrp * 8;
  const int uu = lrow + 16 * w01;  // unit owned in elementwise phase

  // ---- this wave's layer weights in VGPRs (hi/lo bf16) ----
  const float* Wih = layer ? wih1 : wih0;
  const float* Whh = layer ? whh1 : whh0;
  const int ldk = layer ? 32 : 28;

  short8 Wxh[4], Wxl[4], Whh_[4], Whl[4];
#pragma unroll
  for (int tt = 0; tt < 4; ++tt) {
    int n = tt * 2 + w01;
    load_wtile(Wih, ldk, ldk, n, lane, Wxh[tt], Wxl[tt]);
    load_wtile(Whh, 32, 32, n, lane, Whh_[tt], Whl[tt]);
  }

  float c[4] = {0, 0, 0, 0}, h[4] = {0, 0, 0, 0};

  const float* xrow = x + ((size_t)(b0 + lrow)) * T_LEN * D_IN + kb;
  float4 A0 = make_float4(0, 0, 0, 0), A1 = make_float4(0, 0, 0, 0);
  if (layer == 0) {
    A0 = *(const float4*)(xrow);
    if (lgrp < 3) A1 = *(const float4*)(xrow + 4);
  }

  __syncthreads();  // LDS zero-init visible

  for (int s = 0; s < T_LEN + 1; ++s) {
    const int p = s & 1, q = p ^ 1;
    if (layer == 0) {
      if (s < T_LEN) {
        // prefetch x(s+1) - stays in flight across the lds_barrier
        int tn = (s + 1 < T_LEN) ? s + 1 : s;
        float4 N0 = *(const float4*)(xrow + (size_t)tn * D_IN);
        float4 N1 = make_float4(0, 0, 0, 0);
        if (lgrp < 3) N1 = *(const float4*)(xrow + (size_t)tn * D_IN + 4);

        short8 xh, xl;
        {
          float xv[8] = {A0.x, A0.y, A0.z, A0.w, A1.x, A1.y, A1.z, A1.w};
#pragma unroll
          for (int i = 0; i < 8; ++i) {
            short hh_, ll_;
            split_bf16(xv[i], hh_, ll_);
            xh[i] = hh_; xl[i] = ll_;
          }
        }
        short8 ph = *(const short8*)&h1buf[q][0][lrow][kb];
        short8 pl = *(const short8*)&h1buf[q][1][lrow][kb];
        f32x4 acc[4];
#pragma unroll
        for (int tt = 0; tt < 4; ++tt) {
          f32x4 a = {0.f, 0.f, 0.f, 0.f};
          a = MFMA(xh, Wxh[tt], a);
          a = MFMA(xl, Wxh[tt], a);
          a = MFMA(xh, Wxl[tt], a);
          a = MFMA(ph, Whh_[tt], a);
          a = MFMA(pl, Whh_[tt], a);
          a = MFMA(ph, Whl[tt], a);
          acc[tt] = a;
        }
        cell_update(acc, c, h);
#pragma unroll
        for (int r = 0; r < 4; ++r) {
          short hh_, ll_;
          split_bf16(h[r], hh_, ll_);
          int row = lgrp * 4 + r;
          h1buf[p][0][row][uu] = hh_;
          h1buf[p][1][row][uu] = ll_;
        }
        A0 = N0; A1 = N1;
      }
    } else {
      if (s >= 1) {
        short8 ah = *(const short8*)&h1buf[q][0][lrow][kb];
        short8 al = *(const short8*)&h1buf[q][1][lrow][kb];
        short8 ph = *(const short8*)&h2buf[q][0][lrow][kb];
        short8 pl = *(const short8*)&h2buf[q][1][lrow][kb];
        f32x4 acc[4];
#pragma unroll
        for (int tt = 0; tt < 4; ++tt) {
          f32x4 a = {0.f, 0.f, 0.f, 0.f};
          a = MFMA(ah, Wxh[tt], a);
          a = MFMA(al, Wxh[tt], a);
          a = MFMA(ah, Wxl[tt], a);
          a = MFMA(ph, Whh_[tt], a);
          a = MFMA(pl, Whh_[tt], a);
          a = MFMA(ph, Whl[tt], a);
          acc[tt] = a;
        }
        cell_update(acc, c, h);
#pragma unroll
        for (int r = 0; r < 4; ++r) {
          short hh_, ll_;
          split_bf16(h[r], hh_, ll_);
          int row = lgrp * 4 + r;
          h2buf[p][0][row][uu] = hh_;
          h2buf[p][1][row][uu] = ll_;
        }
      }
    }
    lds_barrier();
    // Hazard audit: iter s reads parity q, writes parity p; iter s+1 writes
    // parity q — ordered by this barrier. Global x prefetch intentionally
    // NOT drained; it is consumed (vmcnt auto-wait) next iteration.
  }

  // ---- epilogue: out = h2(T-1) @ wout^T + bout ----
  if (layer == 1) {
#pragma unroll
    for (int r = 0; r < 4; ++r) hf[lgrp * 4 + r][uu] = h[r];
  }
  __syncthreads();

  for (int j = tid; j < 160; j += 256) {
    int row = j / 10, col = j % 10;
    float s = bout[col];
#pragma unroll
    for (int u = 0; u < 32; ++u) s += hf[row][u] * wout[col * 32 + u];
    out[(size_t)(b0 + row) * 10 + col] = s;
  }
}

extern "C" void kernel_launch(void* const* d_in, const int* in_sizes, int n_in,
                              void* d_out, int out_size, void* d_ws, size_t ws_size,
                              hipStream_t stream) {
  const float* x = (const float*)d_in[0];
  const float* wih0 = (const float*)d_in[1];
  const float* whh0 = (const float*)d_in[2];
  const float* wih1 = (const float*)d_in[3];
  const float* whh1 = (const float*)d_in[4];
  const float* wout = (const float*)d_in[5];
  const float* bout = (const float*)d_in[6];
  float* out = (float*)d_out;
  lstm2_pipe<<<256, 256, 0, stream>>>(x, wih0, whh0, wih1, whh1, wout, bout, out);
}